// Round 12
// baseline (148123.901 us; speedup 1.0000x reference)
//
#include <hip/hip_runtime.h>
#include <cstdint>
#include <cstddef>

// ---------------- constants ----------------
#define NB    64      // batch
#define TIN   512
#define TOUT  500
#define NMEL  80
#define ENC   512
#define ATTD  128
#define ARNN  1024
#define DRNN  1024
#define PREN  256
#define NFILT 32
#define KSZ   31
#define CPAD  15

#define MEL_OFF  0
#define GATE_OFF 2560000
#define ALGN_OFF 2592000

// ws float-layout sizes
#define X_SZ      8192000
#define PM_SZ     4194304
#define G1_SZ     1048576   // up to 4 partials of [64][4096]
#define G2_SZ     1048576
#define XATT_SZ   98304
#define XDEC_SZ   163840
#define AC_SZ     65536
#define DC_SZ     65536
#define AW_SZ     32768
#define AWC_SZ    32768
#define TAILH_SZ  49152
#define TAILL_SZ  49152
#define XDH_SZ    81920
#define XDL_SZ    81920
#define PQ_SZ     8192
#define EN_SZ     32768
#define MASK_N    8208384

// packed bf16 weights: [256 ntile][K/32 kchunk][2 hl][512]
// virtual K layouts: pk1 = [x(256)|ctx(512)|ah(1024)]  kc: x[0,8) ctx[8,24) ah[24,56)
//                    pk2 = [ah(1024)|ctx(512)|dh(1024)] kc: ah[0,32) ctx[32,48) dh[48,80)
#define K1TOT   1792
#define K2TOT   2560
#define NCH1    56
#define NCH2    80
#define PK1_N   14680064
#define PK2_N   20971520

typedef unsigned short u16;
typedef __attribute__((ext_vector_type(8))) short bf16x8;
typedef __attribute__((ext_vector_type(4))) float f32x4;

__device__ __forceinline__ uint32_t rotl32(uint32_t v, int r) { return (v << r) | (v >> (32 - r)); }

// fast saturating transcendentals
__device__ __forceinline__ float sigf(float x) { return 1.f / (1.f + __expf(-x)); }
__device__ __forceinline__ float tanhf_fast(float x) {
    float ax = fabsf(x);
    float t = 1.f - 2.f / (__expf(2.f * ax) + 1.f);
    return copysignf(t, x);
}

// Dekker-style split: hi = truncate-to-bf16(v), lo = rn-bf16(v - hi).
__device__ __forceinline__ void split1(float v, u16& h, u16& l) {
    uint32_t u = __float_as_uint(v);
    h = (u16)(u >> 16);
    float r = v - __uint_as_float(u & 0xFFFF0000u);
    uint32_t ru = __float_as_uint(r);
    ru += 0x7FFFu + ((ru >> 16) & 1u);
    l = (u16)(ru >> 16);
}

__device__ __forceinline__ void split8(float4 f0, float4 f1, bf16x8& h, bf16x8& l) {
    float v[8] = { f0.x, f0.y, f0.z, f0.w, f1.x, f1.y, f1.z, f1.w };
#pragma unroll
    for (int i = 0; i < 8; ++i) {
        uint32_t u = __float_as_uint(v[i]);
        h[i] = (short)(u >> 16);
        float r = v[i] - __uint_as_float(u & 0xFFFF0000u);
        uint32_t ru = __float_as_uint(r);
        ru += 0x7FFFu + ((ru >> 16) & 1u);
        l[i] = (short)(ru >> 16);
    }
}

#define MFMA16(a, b, c) __builtin_amdgcn_mfma_f32_16x16x32_bf16(a, b, c, 0, 0, 0)

// JAX threefry2x32
__device__ void tf_block(uint32_t k1, uint32_t k2, uint32_t& x0, uint32_t& x1) {
    uint32_t ks0 = k1, ks1 = k2, ks2 = k1 ^ k2 ^ 0x1BD11BDAu;
    x0 += ks0; x1 += ks1;
#define TFR(r) { x0 += x1; x1 = rotl32(x1, r); x1 ^= x0; }
    TFR(13) TFR(15) TFR(26) TFR(6)   x0 += ks1; x1 += ks2 + 1u;
    TFR(17) TFR(29) TFR(16) TFR(24)  x0 += ks2; x1 += ks0 + 2u;
    TFR(13) TFR(15) TFR(26) TFR(6)   x0 += ks0; x1 += ks1 + 3u;
    TFR(17) TFR(29) TFR(16) TFR(24)  x0 += ks1; x1 += ks2 + 4u;
    TFR(13) TFR(15) TFR(26) TFR(6)   x0 += ks2; x1 += ks0 + 5u;
#undef TFR
}

__global__ __launch_bounds__(256) void mask_kernel(unsigned char* m1, unsigned char* m2) {
    int i = blockIdx.x * 256 + threadIdx.x;
    if (i >= MASK_N) return;
    uint32_t a0 = 0u, a1 = 0u; tf_block(0u, 42u, a0, a1);
    uint32_t b0 = 0u, b1 = 1u; tf_block(0u, 42u, b0, b1);
    uint32_t x0, x1;
    x0 = 0u; x1 = (uint32_t)i; tf_block(a0, a1, x0, x1);
    m1[i] = ((x0 ^ x1) >> 31) == 0u;
    x0 = 0u; x1 = (uint32_t)i; tf_block(b0, b1, x0, x1);
    m2[i] = ((x0 ^ x1) >> 31) == 0u;
}

__global__ __launch_bounds__(256) void prenet1_kernel(
    const float* __restrict__ dec_in, const float* __restrict__ w1,
    const unsigned char* __restrict__ m1, float* __restrict__ x)
{
    int r = blockIdx.x;
    int t = r >> 6, b = r & 63;
    int tid = threadIdx.x;
    __shared__ float ds[NMEL];
    if (tid < NMEL) ds[tid] = (t == 0) ? 0.f : dec_in[(size_t)b * 40000 + tid * 500 + (t - 1)];
    __syncthreads();
    float acc = 0.f;
    const float* w = w1 + tid * NMEL;
#pragma unroll
    for (int k = 0; k < NMEL; ++k) acc += ds[k] * w[k];
    acc = fmaxf(acc, 0.f);
    int flat = r * 256 + tid;
    x[flat] = m1[flat] ? acc * 2.f : 0.f;
}

__global__ __launch_bounds__(256) void prenet2_kernel(
    const float* __restrict__ w2, const unsigned char* __restrict__ m2, float* x)
{
    int r = blockIdx.x;
    int tid = threadIdx.x;
    __shared__ float xs[PREN];
    xs[tid] = x[r * 256 + tid];
    __syncthreads();
    float acc = 0.f;
    const float* w = w2 + tid * PREN;
#pragma unroll 8
    for (int k = 0; k < PREN; ++k) acc += xs[k] * w[k];
    acc = fmaxf(acc, 0.f);
    int flat = r * 256 + tid;
    x[flat] = m2[flat] ? acc * 2.f : 0.f;
}

__global__ __launch_bounds__(128) void pm_kernel(
    const float* __restrict__ memory, const float* __restrict__ wm, float* __restrict__ pm)
{
    int b = blockIdx.x, t = blockIdx.y;
    int tid = threadIdx.x;
    __shared__ float ms[ENC];
    for (int i = tid; i < ENC; i += 128) ms[i] = memory[(size_t)b * (TIN * ENC) + (size_t)t * ENC + i];
    __syncthreads();
    float acc = 0.f;
    const float* w = wm + tid * ENC;
#pragma unroll 8
    for (int k = 0; k < ENC; ++k) acc += ms[k] * w[k];
    pm[(size_t)b * (TIN * ATTD) + t * ATTD + tid] = acc;
}

// one-time weight split+pack (fragment-contiguous B lines)
__global__ __launch_bounds__(256) void wpack_kernel(
    const float* __restrict__ w1, int K1, const float* __restrict__ w2, int K2,
    u16* __restrict__ dst)
{
    const int K = K1 + K2;
    int idx = blockIdx.x * 256 + threadIdx.x;
    if (idx >= 4096 * K) return;
    int n = idx / K, k = idx % K;
    float v = (k < K1) ? w1[n * K1 + k] : w2[n * K2 + (k - K1)];
    u16 h, l;
    split1(v, h, l);
    int tile = n >> 4, kc = k >> 5;
    int lane = (n & 15) + (((k & 31) >> 3) << 4);
    size_t off = ((size_t)(tile * (K >> 5) + kc) * 2) * 512 + lane * 8 + (k & 7);
    dst[off] = h;
    dst[off + 512] = l;
}

// ---------------- fp32 fallback K-split GEMM ----------------
struct SmemGemm { float Xs[32][68]; float Ws[32][68]; };

__device__ void gemm_phase(
    const float* __restrict__ X1, int ldx1, int kx1,
    const float* __restrict__ X2, int ldx2,
    const float* __restrict__ W1, int ldw1, int kw1,
    const float* __restrict__ W2, int ldw2,
    float* __restrict__ outp, int Kq, int blk, SmemGemm& s)
{
    const int tid = threadIdx.x;
    const int n0 = (blk & 63) * 64;
    const int ks = blk >> 6;
    const int kbeg = ks * Kq;
    const int tn = tid & 15, tm = tid >> 4;
    float acc[4][4];
#pragma unroll
    for (int i = 0; i < 4; ++i)
#pragma unroll
        for (int j = 0; j < 4; ++j) acc[i][j] = 0.f;

#pragma unroll 1
    for (int k0 = kbeg; k0 < kbeg + Kq; k0 += 32) {
#pragma unroll
        for (int i = 0; i < 8; ++i) {
            int flat = i * 256 + tid;
            int m = flat >> 5, c = flat & 31;
            int k = k0 + c;
            s.Xs[c][m] = (k < kx1) ? X1[m * ldx1 + k] : X2[m * ldx2 + (k - kx1)];
        }
#pragma unroll
        for (int i = 0; i < 8; ++i) {
            int flat = i * 256 + tid;
            int r = flat >> 5, c = flat & 31;
            int k = k0 + c;
            int n = n0 + r;
            s.Ws[c][r] = (k < kw1) ? W1[n * ldw1 + k] : W2[n * ldw2 + (k - kw1)];
        }
        __syncthreads();
#pragma unroll
        for (int kk = 0; kk < 32; ++kk) {
            float4 xv = *(const float4*)&s.Xs[kk][tm * 4];
            float4 wv = *(const float4*)&s.Ws[kk][tn * 4];
            float xr[4] = { xv.x, xv.y, xv.z, xv.w };
            float wr[4] = { wv.x, wv.y, wv.z, wv.w };
#pragma unroll
            for (int i = 0; i < 4; ++i)
#pragma unroll
                for (int j = 0; j < 4; ++j) acc[i][j] += xr[i] * wr[j];
        }
        __syncthreads();
    }
    float* o = outp + (size_t)ks * 64 * 4096;
#pragma unroll
    for (int i = 0; i < 4; ++i)
#pragma unroll
        for (int j = 0; j < 4; ++j)
            o[(tm * 4 + i) * 4096 + (n0 + tn * 4 + j)] = acc[i][j];
}

__global__ __launch_bounds__(256, 2) void pair_gemm(
    const float* __restrict__ xcat_dec,
    const float* __restrict__ dec_wih, const float* __restrict__ dec_whh,
    float* __restrict__ g2,
    const float* __restrict__ x, const float* __restrict__ xcat_att,
    const float* __restrict__ att_wih, const float* __restrict__ att_whh,
    float* __restrict__ g1, int t)
{
    __shared__ __align__(16) SmemGemm sm;
    const int blk = blockIdx.x;
    if (blk < 256) {
        if (t < 0) return;
        gemm_phase(xcat_dec, 2560, 2560, xcat_dec, 2560,
                   dec_wih, 1536, 1536, dec_whh, 1024, g2, 640, blk, sm);
    } else {
        const int tn = t + 1;
        if (tn >= TOUT) return;
        gemm_phase(x + (size_t)tn * (NB * PREN), PREN, PREN, xcat_att, 1536,
                   att_wih, 768, 768, att_whh, 1024, g1, 448, blk - 256, sm);
    }
}

// ---------------- MFMA gemm inner body over a kc list ----------------
__device__ __forceinline__ void mfma_tile_run(
    const u16* __restrict__ Ah, const u16* __restrict__ Al, int aoff,
    const float* __restrict__ xr,
    const u16* __restrict__ bp, int kc_beg, int nchunk, int kc_wrap_at, int kc_wrap_to,
    f32x4& acc, int lane)
{
    const int kg = lane >> 4;
#pragma unroll 4
    for (int i = 0; i < nchunk; ++i) {
        int kc = kc_beg + i;
        if (kc >= kc_wrap_at) kc = kc_wrap_to + (kc - kc_wrap_at);
        const int k = kc * 32 + kg * 8;
        bf16x8 ah, al;
        if (xr && k < 256) {
            float4 f0 = *(const float4*)(xr + k);
            float4 f1 = *(const float4*)(xr + k + 4);
            split8(f0, f1, ah, al);
        } else {
            ah = *(const bf16x8*)(Ah + (k - aoff));
            al = *(const bf16x8*)(Al + (k - aoff));
        }
        const u16* c0 = bp + (size_t)kc * 1024;
        bf16x8 bh = *(const bf16x8*)c0;
        bf16x8 bl = *(const bf16x8*)(c0 + 512);
        acc = MFMA16(ah, bh, acc); acc = MFMA16(ah, bl, acc); acc = MFMA16(al, bh, acc);
    }
}

__device__ __forceinline__ void mfma_store(float* o, f32x4 acc, int tile, int wave, int lane)
{
    const int n0 = tile * 16;
    const int mbase = wave * 16 + (lane >> 4) * 4;
    const int lr = lane & 15;
#pragma unroll
    for (int r = 0; r < 4; ++r)
        o[(mbase + r) * 4096 + n0 + lr] = acc[r];
}

// ---------------- energies device body (fallback path) ----------------
__device__ void energies_body(
    int b, int tc,
    const float* __restrict__ aw, const float* __restrict__ awc,
    const float* __restrict__ lc, const float* __restrict__ ld,
    const float* __restrict__ vvec, const float* __restrict__ pq,
    const float* __restrict__ pm, float* __restrict__ energ)
{
    const int t0 = tc * 64;
    const int tid = threadIdx.x;
    __shared__ float awin[96], awcin[96];
    __shared__ float lcs[NFILT * 62];
    __shared__ float locs[64 * 33];
    __shared__ float pqs[ATTD], vs[ATTD];
    __shared__ float ldm[ATTD * 33];

    for (int i = tid; i < 94; i += 256) {
        int t = t0 + i - CPAD;
        bool ok = (t >= 0 && t < TIN);
        awin[i]  = ok ? aw[b * TIN + t]  : 0.f;
        awcin[i] = ok ? awc[b * TIN + t] : 0.f;
    }
    for (int i = tid; i < NFILT * 62; i += 256) lcs[i] = lc[i];
    for (int i = tid; i < ATTD * NFILT; i += 256) ldm[(i >> 5) * 33 + (i & 31)] = ld[i];
    if (tid < ATTD) { pqs[tid] = pq[b * ATTD + tid]; vs[tid] = vvec[tid]; }
    __syncthreads();

    for (int idx = tid; idx < 64 * 32; idx += 256) {
        int tl = idx >> 5, f = idx & 31;
        const float* w0 = lcs + f * 62;
        float s = 0.f;
#pragma unroll
        for (int k = 0; k < KSZ; ++k)
            s += awin[tl + k] * w0[k] + awcin[tl + k] * w0[31 + k];
        locs[tl * 33 + f] = s;
    }
    __syncthreads();

    const int tl = tid >> 2, q = tid & 3;
    const int a0 = q * 32;
    const float* pmrow = pm + (size_t)b * (TIN * ATTD) + (size_t)(t0 + tl) * ATTD + a0;
    const float* lt = locs + tl * 33;
    float4 pv[8];
#pragma unroll
    for (int u = 0; u < 8; ++u) pv[u] = *(const float4*)&pmrow[u * 4];
    float e = 0.f;
#pragma unroll
    for (int aa = 0; aa < 32; ++aa) {
        int a = a0 + aa;
        float sv = pqs[a] + ((const float*)pv)[aa];
        const float* lrow = ldm + a * 33;
#pragma unroll
        for (int f = 0; f < NFILT; ++f) sv += lt[f] * lrow[f];
        e += vs[a] * tanhf_fast(sv);
    }
    e += __shfl_xor(e, 1);
    e += __shfl_xor(e, 2);
    if (q == 0) energ[b * TIN + t0 + tl] = e;
}

// ---------------- MEGA: attn chain per b [blk 0-63] || gemm2-early [64-575] || gemm1-early [576-1087]
struct MegaP1 {
    float awin[544]; float awcin[544];
    float lcs[NFILT * 62];
    float ldm[ATTD * 33];
    float locs[64 * 33];
    float pqs[ATTD]; float vs[ATTD];
};
struct MegaP2 { float ms[8][ENC]; };
union MegaU { MegaP1 p1; MegaP2 p2; };

__global__ __launch_bounds__(256) void mega_mid(
    const float* __restrict__ aw, float* __restrict__ awc,
    const float* __restrict__ lc, const float* __restrict__ ld,
    const float* __restrict__ vvec, const float* __restrict__ pq,
    const float* __restrict__ pm, const int* __restrict__ mlen,
    const float* __restrict__ memory, float* __restrict__ out_align,
    float* __restrict__ aw_out,
    float* __restrict__ xcat_att, float* __restrict__ xcat_dec,
    u16* __restrict__ tailh, u16* __restrict__ taill,
    u16* __restrict__ xdech, u16* __restrict__ xdecl,
    const u16* __restrict__ pk2, float* __restrict__ g2,
    const float* __restrict__ x,
    const u16* __restrict__ pk1, float* __restrict__ g1, int t)
{
    const int blk = blockIdx.x;
    const int tid = threadIdx.x;

    if (blk >= 64) {
        // ---- gemm-early halves (no LDS use) ----
        const int wave = tid >> 6, lane = tid & 63;
        const int mrow = wave * 16 + (lane & 15);
        f32x4 acc = {0.f, 0.f, 0.f, 0.f};
        if (blk < 576) {
            if (t < 0) return;
            const int r = blk - 64;
            const int tile = r & 255, ks = r >> 8;
            const u16* bp = pk2 + (size_t)tile * NCH2 * 1024 + lane * 8;
            mfma_tile_run(xdech + mrow * 2560, xdecl + mrow * 2560, 0, nullptr,
                          bp, ks == 0 ? 0 : 48, 32, 1000, 0, acc, lane);
            mfma_store(g2 + (size_t)ks * 262144, acc, tile, wave, lane);
        } else {
            const int tn = t + 1;
            if (tn >= TOUT) return;
            const int r = blk - 576;
            const int tile = r & 255, ks = r >> 8;
            const u16* bp = pk1 + (size_t)tile * NCH1 * 1024 + lane * 8;
            const float* xr = x + ((size_t)tn * 64 + mrow) * 256;
            mfma_tile_run(tailh + mrow * 1536, taill + mrow * 1536, 256, xr,
                          bp, ks == 0 ? 24 : 44, 20, 56, 0, acc, lane);
            mfma_store(g1 + (size_t)ks * 262144, acc, tile, wave, lane);
        }
        return;
    }

    // ---- attn chain for batch row b ----
    if (t < 0) return;
    const int b = blk;
    __shared__ __align__(16) MegaU mu;
    __shared__ float es[TIN];
    __shared__ float red[256];

    // stage inputs (full row + conv halo)
    for (int i = tid; i < 542; i += 256) {
        int tt = i - CPAD;
        bool ok = (tt >= 0 && tt < TIN);
        mu.p1.awin[i]  = ok ? aw[b * TIN + tt]  : 0.f;
        mu.p1.awcin[i] = ok ? awc[b * TIN + tt] : 0.f;
    }
    for (int i = tid; i < NFILT * 62; i += 256) mu.p1.lcs[i] = lc[i];
    for (int i = tid; i < ATTD * NFILT; i += 256) mu.p1.ldm[(i >> 5) * 33 + (i & 31)] = ld[i];
    if (tid < ATTD) { mu.p1.pqs[tid] = pq[b * ATTD + tid]; mu.p1.vs[tid] = vvec[tid]; }
    __syncthreads();

    // energies in 8 chunks of 64 t, results to LDS es[]
#pragma unroll 1
    for (int tc = 0; tc < 8; ++tc) {
        const int t0 = tc * 64;
        for (int idx = tid; idx < 64 * 32; idx += 256) {
            int tl = idx >> 5, f = idx & 31;
            const float* w0 = mu.p1.lcs + f * 62;
            float s = 0.f;
#pragma unroll
            for (int k = 0; k < KSZ; ++k)
                s += mu.p1.awin[t0 + tl + k] * w0[k] + mu.p1.awcin[t0 + tl + k] * w0[31 + k];
            mu.p1.locs[tl * 33 + f] = s;
        }
        __syncthreads();
        const int tl = tid >> 2, q = tid & 3;
        const int a0 = q * 32;
        const float* pmrow = pm + (size_t)b * (TIN * ATTD) + (size_t)(t0 + tl) * ATTD + a0;
        const float* lt = mu.p1.locs + tl * 33;
        float4 pv[8];
#pragma unroll
        for (int u = 0; u < 8; ++u) pv[u] = *(const float4*)&pmrow[u * 4];
        float e = 0.f;
#pragma unroll
        for (int aa = 0; aa < 32; ++aa) {
            int a = a0 + aa;
            float sv = mu.p1.pqs[a] + ((const float*)pv)[aa];
            const float* lrow = mu.p1.ldm + a * 33;
#pragma unroll
            for (int f = 0; f < NFILT; ++f) sv += lt[f] * lrow[f];
            e += mu.p1.vs[a] * tanhf_fast(sv);
        }
        e += __shfl_xor(e, 1);
        e += __shfl_xor(e, 2);
        if (q == 0) es[t0 + tl] = e;
        __syncthreads();
    }

    // masked softmax over es[512]
    const int len = mlen[b];
    float e1 = (tid < len) ? es[tid] : -INFINITY;
    float e2 = (tid + 256 < len) ? es[tid + 256] : -INFINITY;
    red[tid] = fmaxf(e1, e2);
    __syncthreads();
    for (int s = 128; s > 0; s >>= 1) {
        if (tid < s) red[tid] = fmaxf(red[tid], red[tid + s]);
        __syncthreads();
    }
    const float mx = red[0];
    __syncthreads();
    float p1 = __expf(e1 - mx);
    float p2 = __expf(e2 - mx);
    red[tid] = p1 + p2;
    __syncthreads();
    for (int s = 128; s > 0; s >>= 1) {
        if (tid < s) red[tid] += red[tid + s];
        __syncthreads();
    }
    const float inv = 1.f / red[0];
    p1 *= inv; p2 *= inv;
    es[tid] = p1; es[tid + 256] = p2;

    aw_out[b * TIN + tid] = p1;        aw_out[b * TIN + tid + 256] = p2;
    awc[b * TIN + tid] += p1;          awc[b * TIN + tid + 256] += p2;
    size_t ao = (size_t)b * (TOUT * TIN) + (size_t)t * TIN;
    out_align[ao + tid] = p1;          out_align[ao + tid + 256] = p2;

    // ctx[d] = sum_t p[t] * memory[b,t,d] (round-2 staged pattern; union phase 2)
    float c1 = 0.f, c2 = 0.f;
    const float* mb = memory + (size_t)b * (TIN * ENC);
#pragma unroll 1
    for (int tc = 0; tc < TIN; tc += 8) {
        __syncthreads();
#pragma unroll
        for (int i = 0; i < 16; ++i) {
            int flat = i * 256 + tid;
            int tt = flat >> 9, d = flat & 511;
            mu.p2.ms[tt][d] = mb[(size_t)(tc + tt) * ENC + d];
        }
        __syncthreads();
#pragma unroll
        for (int j = 0; j < 8; ++j) {
            float a_ = es[tc + j];
            c1 += a_ * mu.p2.ms[j][tid];
            c2 += a_ * mu.p2.ms[j][tid + 256];
        }
    }
    xcat_att[b * 1536 + tid] = c1;
    xcat_att[b * 1536 + 256 + tid] = c2;
    xcat_dec[b * 2560 + 1024 + tid] = c1;
    xcat_dec[b * 2560 + 1024 + 256 + tid] = c2;
    u16 h1, l1, h2, l2;
    split1(c1, h1, l1); split1(c2, h2, l2);
    tailh[b * 1536 + tid] = h1;        taill[b * 1536 + tid] = l1;
    tailh[b * 1536 + 256 + tid] = h2;  taill[b * 1536 + 256 + tid] = l2;
    xdech[b * 2560 + 1024 + tid] = h1;        xdecl[b * 2560 + 1024 + tid] = l1;
    xdech[b * 2560 + 1024 + 256 + tid] = h2;  xdecl[b * 2560 + 1024 + 256 + tid] = l2;
}

// ---------------- LATE: ctx K-chunks -> partial 2 of g2(t) and g1(t+1) ----------------
__global__ __launch_bounds__(256) void gemm_late(
    const u16* __restrict__ xdech, const u16* __restrict__ xdecl,
    const u16* __restrict__ pk2, float* __restrict__ g2,
    const u16* __restrict__ tailh, const u16* __restrict__ taill,
    const u16* __restrict__ pk1, float* __restrict__ g1, int t)
{
    const int blk = blockIdx.x;
    const int tid = threadIdx.x;
    const int wave = tid >> 6, lane = tid & 63;
    const int mrow = wave * 16 + (lane & 15);
    f32x4 acc = {0.f, 0.f, 0.f, 0.f};

    if (blk < 256) {
        if (t < 0) return;
        const int tile = blk;
        const u16* bp = pk2 + (size_t)tile * NCH2 * 1024 + lane * 8;
        mfma_tile_run(xdech + mrow * 2560, xdecl + mrow * 2560, 0, nullptr,
                      bp, 32, 16, 1000, 0, acc, lane);
        mfma_store(g2 + (size_t)2 * 262144, acc, tile, wave, lane);
    } else {
        const int tn = t + 1;
        if (tn >= TOUT) return;
        const int tile = blk - 256;
        const u16* bp = pk1 + (size_t)tile * NCH1 * 1024 + lane * 8;
        mfma_tile_run(tailh + mrow * 1536, taill + mrow * 1536, 256, nullptr,
                      bp, 8, 16, 1000, 0, acc, lane);
        mfma_store(g1 + (size_t)2 * 262144, acc, tile, wave, lane);
    }
}

// ---------------- L1: att_pointwise(t) || dec_pointwise+proj(t-1) ----------------
__global__ __launch_bounds__(256) void pair_pw(
    const float* __restrict__ g1, const float* __restrict__ att_bih, const float* __restrict__ att_bhh,
    float* __restrict__ ac, float* __restrict__ xcat_att, float* __restrict__ xcat_dec,
    const float* __restrict__ wq, float* __restrict__ pq,
    const float* __restrict__ g2, const float* __restrict__ dec_bih, const float* __restrict__ dec_bhh,
    float* __restrict__ dc, const float* __restrict__ proj_w, const float* __restrict__ proj_b,
    const float* __restrict__ gate_w, const float* __restrict__ gate_b,
    float* __restrict__ out,
    u16* __restrict__ tailh, u16* __restrict__ taill,
    u16* __restrict__ xdech, u16* __restrict__ xdecl,
    int nsplit, int t)
{
    const int tid = threadIdx.x;
    __shared__ float sbuf[1536];
    __shared__ float red[256];

    if (blockIdx.x < 64) {
        if (t >= TOUT) return;
        const int b = blockIdx.x;
#pragma unroll
        for (int q = 0; q < 4; ++q) {
            int j = q * 256 + tid;
            float gi = att_bih[j] + att_bhh[j];
            float gf = att_bih[1024 + j] + att_bhh[1024 + j];
            float gg = att_bih[2048 + j] + att_bhh[2048 + j];
            float go = att_bih[3072 + j] + att_bhh[3072 + j];
            for (int s = 0; s < nsplit; ++s) {
                const float* g = g1 + (size_t)s * 262144 + b * 4096;
                gi += g[j]; gf += g[1024 + j]; gg += g[2048 + j]; go += g[3072 + j];
            }
            float c = sigf(gf) * ac[b * 1024 + j] + sigf(gi) * tanhf_fast(gg);
            float h = sigf(go) * tanhf_fast(c);
            ac[b * 1024 + j] = c;
            xcat_att[b * 1536 + 512 + j] = h;
            xcat_dec[b * 2560 + j] = h;
            u16 hh, hl; split1(h, hh, hl);
            tailh[b * 1536 + 512 + j] = hh;  taill[b * 1536 + 512 + j] = hl;
            xdech[b * 2560 + j] = hh;        xdecl[b * 2560 + j] = hl;
            sbuf[j] = h;
        }
        __syncthreads();
        const int a = tid & 127, half = tid >> 7;
        const float* wr = wq + a * 1024 + half * 512;
        const float* hh = sbuf + half * 512;
        float s0 = 0.f, s1 = 0.f, s2 = 0.f, s3 = 0.f;
#pragma unroll 4
        for (int k = 0; k < 512; k += 16) {
            float4 w0 = *(const float4*)&wr[k],      h0 = *(const float4*)&hh[k];
            float4 w1 = *(const float4*)&wr[k + 4],  h1 = *(const float4*)&hh[k + 4];
            float4 w2 = *(const float4*)&wr[k + 8],  h2 = *(const float4*)&hh[k + 8];
            float4 w3 = *(const float4*)&wr[k + 12], h3 = *(const float4*)&hh[k + 12];
            s0 += h0.x * w0.x + h0.y * w0.y + h0.z * w0.z + h0.w * w0.w;
            s1 += h1.x * w1.x + h1.y * w1.y + h1.z * w1.z + h1.w * w1.w;
            s2 += h2.x * w2.x + h2.y * w2.y + h2.z * w2.z + h2.w * w2.w;
            s3 += h3.x * w3.x + h3.y * w3.y + h3.z * w3.z + h3.w * w3.w;
        }
        red[tid] = (s0 + s1) + (s2 + s3);
        __syncthreads();
        if (half == 0) pq[b * 128 + a] = red[a] + red[a + 128];
    } else {
        if (t < 1) return;
        const int b = blockIdx.x - 64;
        const int ts = t - 1;
#pragma unroll
        for (int q = 0; q < 4; ++q) {
            int j = q * 256 + tid;
            float gi = dec_bih[j] + dec_bhh[j];
            float gf = dec_bih[1024 + j] + dec_bhh[1024 + j];
            float gg = dec_bih[2048 + j] + dec_bhh[2048 + j];
            float go = dec_bih[3072 + j] + dec_bhh[3072 + j];
            for (int s = 0; s < nsplit; ++s) {
                const float* g = g2 + (size_t)s * 262144 + b * 4096;
                gi += g[j]; gf += g[1024 + j]; gg += g[2048 + j]; go += g[3072 + j];
            }
            float c = sigf(gf) * dc[b * 1024 + j] + sigf(gi) * tanhf_fast(gg);
            float h = sigf(go) * tanhf_fast(c);
            dc[b * 1024 + j] = c;
            xcat_dec[b * 2560 + 1536 + j] = h;
            u16 hh, hl; split1(h, hh, hl);
            xdech[b * 2560 + 1536 + j] = hh;  xdecl[b * 2560 + 1536 + j] = hl;
            sbuf[j] = h;
        }
        for (int i = tid; i < 512; i += 256) sbuf[1024 + i] = xcat_dec[b * 2560 + 1024 + i];
        __syncthreads();
        const int o = tid >> 1, half = tid & 1;
        float accv = 0.f;
        if (o <= 80) {
            const float* w = (o < 80) ? (proj_w + o * 1536) : gate_w;
            const float* sv = sbuf + half * 768;
            const float* wv = w + half * 768;
            float s0 = 0.f, s1 = 0.f, s2 = 0.f, s3 = 0.f;
#pragma unroll 4
            for (int k = 0; k < 768; k += 16) {
                float4 a0 = *(const float4*)&sv[k],      b0 = *(const float4*)&wv[k];
                float4 a1 = *(const float4*)&sv[k + 4],  b1 = *(const float4*)&wv[k + 4];
                float4 a2 = *(const float4*)&sv[k + 8],  b2 = *(const float4*)&wv[k + 8];
                float4 a3 = *(const float4*)&sv[k + 12], b3 = *(const float4*)&wv[k + 12];
                s0 += a0.x * b0.x + a0.y * b0.y + a0.z * b0.z + a0.w * b0.w;
                s1 += a1.x * b1.x + a1.y * b1.y + a1.z * b1.z + a1.w * b1.w;
                s2 += a2.x * b2.x + a2.y * b2.y + a2.z * b2.z + a2.w * b2.w;
                s3 += a3.x * b3.x + a3.y * b3.y + a3.z * b3.z + a3.w * b3.w;
            }
            accv = (s0 + s1) + (s2 + s3);
        }
        red[tid] = accv;
        __syncthreads();
        if (half == 0 && o <= 80) {
            float r = red[tid] + red[tid + 1];
            if (o < 80)
                out[MEL_OFF + (size_t)b * (TOUT * NMEL) + (size_t)ts * NMEL + o] = r + proj_b[o];
            else
                out[GATE_OFF + (size_t)b * TOUT + ts] = r + gate_b[0];
        }
    }
}

// ---------------- fallback kernels (fp32 path) ----------------
__global__ __launch_bounds__(256) void energies_kernel(
    const float* __restrict__ aw, const float* __restrict__ awc,
    const float* __restrict__ lc, const float* __restrict__ ld,
    const float* __restrict__ vvec, const float* __restrict__ pq,
    const float* __restrict__ pm, float* __restrict__ energ)
{
    energies_body(blockIdx.x >> 3, blockIdx.x & 7, aw, awc, lc, ld, vvec, pq, pm, energ);
}

__global__ __launch_bounds__(256) void softmax_ctx_kernel(
    const float* __restrict__ energ, const int* __restrict__ mlen,
    const float* __restrict__ memory,
    float* __restrict__ aw, float* __restrict__ awc,
    float* __restrict__ out_align, int t_step,
    float* __restrict__ xcat_att, float* __restrict__ xcat_dec,
    u16* __restrict__ tailh, u16* __restrict__ taill,
    u16* __restrict__ xdech, u16* __restrict__ xdecl)
{
    const int b = blockIdx.x >> 3, dq = blockIdx.x & 7;
    const int tid = threadIdx.x;
    const int len = mlen[b];
    __shared__ float es[TIN];
    __shared__ float red[256];

    float e1 = (tid < len) ? energ[b * TIN + tid] : -INFINITY;
    float e2 = (tid + 256 < len) ? energ[b * TIN + tid + 256] : -INFINITY;
    red[tid] = fmaxf(e1, e2);
    __syncthreads();
    for (int s = 128; s > 0; s >>= 1) {
        if (tid < s) red[tid] = fmaxf(red[tid], red[tid + s]);
        __syncthreads();
    }
    const float mx = red[0];
    __syncthreads();
    float p1 = __expf(e1 - mx);
    float p2 = __expf(e2 - mx);
    red[tid] = p1 + p2;
    __syncthreads();
    for (int s = 128; s > 0; s >>= 1) {
        if (tid < s) red[tid] += red[tid + s];
        __syncthreads();
    }
    const float inv = 1.f / red[0];
    p1 *= inv; p2 *= inv;
    es[tid] = p1; es[tid + 256] = p2;
    __syncthreads();

    if (tid < 64) {
        int tt = dq * 64 + tid;
        float p = es[tt];
        aw[b * TIN + tt] = p;
        awc[b * TIN + tt] += p;
        out_align[(size_t)b * (TOUT * TIN) + (size_t)t_step * TIN + tt] = p;
    }

    const int d = dq * 64 + (tid & 63), th = tid >> 6;
    const float* mb = memory + (size_t)b * (TIN * ENC);
    float accv = 0.f;
#pragma unroll 4
    for (int tt = th * 128; tt < th * 128 + 128; ++tt)
        accv += es[tt] * mb[(size_t)tt * ENC + d];
    red[tid] = accv;
    __syncthreads();
    if (tid < 64) {
        float cv = (red[tid] + red[tid + 64]) + (red[tid + 128] + red[tid + 192]);
        int dd = dq * 64 + tid;
        xcat_att[b * 1536 + dd] = cv;
        xcat_dec[b * 2560 + 1024 + dd] = cv;
        u16 h, l; split1(cv, h, l);
        tailh[b * 1536 + dd] = h;        taill[b * 1536 + dd] = l;
        xdech[b * 2560 + 1024 + dd] = h; xdecl[b * 2560 + 1024 + dd] = l;
    }
}

extern "C" void kernel_launch(void* const* d_in, const int* in_sizes, int n_in,
                              void* d_out, int out_size, void* d_ws, size_t ws_size,
                              hipStream_t stream) {
    const float* memory   = (const float*)d_in[0];
    const float* dec_in   = (const float*)d_in[1];
    const int*   mlen     = (const int*)d_in[2];
    const float* pw1      = (const float*)d_in[3];
    const float* pw2      = (const float*)d_in[4];
    const float* att_wih  = (const float*)d_in[5];
    const float* att_whh  = (const float*)d_in[6];
    const float* att_bih  = (const float*)d_in[7];
    const float* att_bhh  = (const float*)d_in[8];
    const float* wq       = (const float*)d_in[9];
    const float* wm       = (const float*)d_in[10];
    const float* v        = (const float*)d_in[11];
    const float* loc_conv = (const float*)d_in[12];
    const float* loc_dense= (const float*)d_in[13];
    const float* dec_wih  = (const float*)d_in[14];
    const float* dec_whh  = (const float*)d_in[15];
    const float* dec_bih  = (const float*)d_in[16];
    const float* dec_bhh  = (const float*)d_in[17];
    const float* proj_w   = (const float*)d_in[18];
    const float* proj_b   = (const float*)d_in[19];
    const float* gate_w   = (const float*)d_in[20];
    const float* gate_b   = (const float*)d_in[21];
    float* out = (float*)d_out;

    // ---- ws layout ----
    float* x        = (float*)d_ws;
    float* pm       = x + X_SZ;
    float* g1       = pm + PM_SZ;
    float* g2       = g1 + G1_SZ;
    float* xcat_att = g2 + G2_SZ;          // zero-block start
    float* xcat_dec = xcat_att + XATT_SZ;
    float* ac       = xcat_dec + XDEC_SZ;
    float* dc       = ac + AC_SZ;
    float* aw       = dc + DC_SZ;
    float* awc      = aw + AW_SZ;
    float* tailh_f  = awc + AWC_SZ;
    float* taill_f  = tailh_f + TAILH_SZ;
    float* xdech_f  = taill_f + TAILL_SZ;
    float* xdecl_f  = xdech_f + XDH_SZ;    // zero-block end
    float* pq       = xdecl_f + XDL_SZ;
    float* energ    = pq + PQ_SZ;
    unsigned char* m1 = (unsigned char*)(energ + EN_SZ);
    unsigned char* m2 = m1 + MASK_N;
    u16* pk1 = (u16*)(m2 + MASK_N);
    u16* pk2 = pk1 + PK1_N;

    u16* tailh = (u16*)tailh_f;  u16* taill = (u16*)taill_f;
    u16* xdech = (u16*)xdech_f;  u16* xdecl = (u16*)xdecl_f;

    size_t need_base = (size_t)(m2 + MASK_N - (unsigned char*)d_ws);
    size_t need_full = (size_t)((unsigned char*)(pk2 + PK2_N) - (unsigned char*)d_ws);
    if (ws_size < need_base) return;
    const bool use_mfma = (ws_size >= need_full);
    const int nsplit = use_mfma ? 3 : 4;

    // zero recurrent state (xcat_att .. xdecl contiguous)
    size_t state_floats = (size_t)XATT_SZ + XDEC_SZ + AC_SZ + DC_SZ + AW_SZ + AWC_SZ
                        + TAILH_SZ + TAILL_SZ + XDH_SZ + XDL_SZ;
    hipMemsetAsync(xcat_att, 0, state_floats * sizeof(float), stream);

    // one-time: dropout masks, prenet, processed memory, weight pack
    mask_kernel<<<(MASK_N + 255) / 256, 256, 0, stream>>>(m1, m2);
    prenet1_kernel<<<TOUT * NB, 256, 0, stream>>>(dec_in, pw1, m1, x);
    prenet2_kernel<<<TOUT * NB, 256, 0, stream>>>(pw2, m2, x);
    pm_kernel<<<dim3(NB, TIN), 128, 0, stream>>>(memory, wm, pm);
    if (use_mfma) {
        wpack_kernel<<<(4096 * K1TOT + 255) / 256, 256, 0, stream>>>(att_wih, 768, att_whh, 1024, pk1);
        wpack_kernel<<<(4096 * K2TOT + 255) / 256, 256, 0, stream>>>(dec_wih, 1536, dec_whh, 1024, pk2);
    }

    float* out_align = out + ALGN_OFF;

    // prologue: gemm1(0) early + late (on zeroed state)
    if (use_mfma) {
        mega_mid<<<1088, 256, 0, stream>>>(aw, awc, loc_conv, loc_dense, v, pq, pm, mlen,
                                           memory, out_align, aw,
                                           xcat_att, xcat_dec, tailh, taill, xdech, xdecl,
                                           pk2, g2, x, pk1, g1, -1);
        gemm_late<<<512, 256, 0, stream>>>(xdech, xdecl, pk2, g2, tailh, taill, pk1, g1, -1);
    } else {
        pair_gemm<<<512, 256, 0, stream>>>(xcat_dec, dec_wih, dec_whh, g2,
                                           x, xcat_att, att_wih, att_whh, g1, -1);
    }

    for (int t = 0; t < TOUT; ++t) {
        pair_pw<<<128, 256, 0, stream>>>(g1, att_bih, att_bhh, ac, xcat_att, xcat_dec, wq, pq,
                                         g2, dec_bih, dec_bhh, dc, proj_w, proj_b,
                                         gate_w, gate_b, out, tailh, taill, xdech, xdecl,
                                         nsplit, t);
        if (use_mfma) {
            // attn chain (energies+softmax+ctx) || gemm2-early(t) || gemm1-early(t+1)
            mega_mid<<<1088, 256, 0, stream>>>(aw, awc, loc_conv, loc_dense, v, pq, pm, mlen,
                                               memory, out_align, aw,
                                               xcat_att, xcat_dec, tailh, taill, xdech, xdecl,
                                               pk2, g2, x, pk1, g1, t);
            // ctx K-chunks of both gemms
            gemm_late<<<512, 256, 0, stream>>>(xdech, xdecl, pk2, g2, tailh, taill, pk1, g1, t);
        } else {
            energies_kernel<<<512, 256, 0, stream>>>(aw, awc, loc_conv, loc_dense, v, pq, pm, energ);
            softmax_ctx_kernel<<<512, 256, 0, stream>>>(energ, mlen, memory, aw, awc, out_align, t,
                                                        xcat_att, xcat_dec, tailh, taill, xdech, xdecl);
            pair_gemm<<<512, 256, 0, stream>>>(xcat_dec, dec_wih, dec_whh, g2,
                                               x, xcat_att, att_wih, att_whh, g1, t);
        }
    }
    // epilogue: dec_pointwise+proj for t=499
    pair_pw<<<128, 256, 0, stream>>>(g1, att_bih, att_bhh, ac, xcat_att, xcat_dec, wq, pq,
                                     g2, dec_bih, dec_bhh, dc, proj_w, proj_b,
                                     gate_w, gate_b, out, tailh, taill, xdech, xdecl,
                                     nsplit, TOUT);
}

// Round 13
// 50232.599 us; speedup vs baseline: 2.9488x; 2.9488x over previous
//
#include <hip/hip_runtime.h>
#include <cstdint>
#include <cstddef>

// ---------------- constants ----------------
#define NB    64      // batch
#define TIN   512
#define TOUT  500
#define NMEL  80
#define ENC   512
#define ATTD  128
#define ARNN  1024
#define DRNN  1024
#define PREN  256
#define NFILT 32
#define KSZ   31
#define CPAD  15

#define MEL_OFF  0
#define GATE_OFF 2560000
#define ALGN_OFF 2592000

// ws float-layout sizes
#define X_SZ      8192000
#define PM_SZ     4194304
#define G1_SZ     1048576   // up to 4 partials of [64][4096]
#define G2_SZ     1048576
#define XATT_SZ   98304
#define XDEC_SZ   163840
#define AC_SZ     65536
#define DC_SZ     65536
#define AW_SZ     32768
#define AWC_SZ    32768
#define TAILH_SZ  49152
#define TAILL_SZ  49152
#define XDH_SZ    81920
#define XDL_SZ    81920
#define PQ_SZ     8192
#define EN_SZ     32768
#define MASK_N    8208384

// packed bf16 weights: [256 ntile][K/32 kchunk][2 hl][512]
// virtual K layouts: pk1 = [x(256)|ctx(512)|ah(1024)]  kc: x[0,8) ctx[8,24) ah[24,56)
//                    pk2 = [ah(1024)|ctx(512)|dh(1024)] kc: ah[0,32) ctx[32,48) dh[48,80)
#define K1TOT   1792
#define K2TOT   2560
#define NCH1    56
#define NCH2    80
#define PK1_N   14680064
#define PK2_N   20971520

typedef unsigned short u16;
typedef __attribute__((ext_vector_type(8))) short bf16x8;
typedef __attribute__((ext_vector_type(4))) float f32x4;

__device__ __forceinline__ uint32_t rotl32(uint32_t v, int r) { return (v << r) | (v >> (32 - r)); }

// fast saturating transcendentals
__device__ __forceinline__ float sigf(float x) { return 1.f / (1.f + __expf(-x)); }
__device__ __forceinline__ float tanhf_fast(float x) {
    float ax = fabsf(x);
    float t = 1.f - 2.f / (__expf(2.f * ax) + 1.f);
    return copysignf(t, x);
}

// Dekker-style split: hi = truncate-to-bf16(v), lo = rn-bf16(v - hi).
__device__ __forceinline__ void split1(float v, u16& h, u16& l) {
    uint32_t u = __float_as_uint(v);
    h = (u16)(u >> 16);
    float r = v - __uint_as_float(u & 0xFFFF0000u);
    uint32_t ru = __float_as_uint(r);
    ru += 0x7FFFu + ((ru >> 16) & 1u);
    l = (u16)(ru >> 16);
}

__device__ __forceinline__ void split8(float4 f0, float4 f1, bf16x8& h, bf16x8& l) {
    float v[8] = { f0.x, f0.y, f0.z, f0.w, f1.x, f1.y, f1.z, f1.w };
#pragma unroll
    for (int i = 0; i < 8; ++i) {
        uint32_t u = __float_as_uint(v[i]);
        h[i] = (short)(u >> 16);
        float r = v[i] - __uint_as_float(u & 0xFFFF0000u);
        uint32_t ru = __float_as_uint(r);
        ru += 0x7FFFu + ((ru >> 16) & 1u);
        l[i] = (short)(ru >> 16);
    }
}

#define MFMA16(a, b, c) __builtin_amdgcn_mfma_f32_16x16x32_bf16(a, b, c, 0, 0, 0)

// JAX threefry2x32
__device__ void tf_block(uint32_t k1, uint32_t k2, uint32_t& x0, uint32_t& x1) {
    uint32_t ks0 = k1, ks1 = k2, ks2 = k1 ^ k2 ^ 0x1BD11BDAu;
    x0 += ks0; x1 += ks1;
#define TFR(r) { x0 += x1; x1 = rotl32(x1, r); x1 ^= x0; }
    TFR(13) TFR(15) TFR(26) TFR(6)   x0 += ks1; x1 += ks2 + 1u;
    TFR(17) TFR(29) TFR(16) TFR(24)  x0 += ks2; x1 += ks0 + 2u;
    TFR(13) TFR(15) TFR(26) TFR(6)   x0 += ks0; x1 += ks1 + 3u;
    TFR(17) TFR(29) TFR(16) TFR(24)  x0 += ks1; x1 += ks2 + 4u;
    TFR(13) TFR(15) TFR(26) TFR(6)   x0 += ks2; x1 += ks0 + 5u;
#undef TFR
}

__global__ __launch_bounds__(256) void mask_kernel(unsigned char* m1, unsigned char* m2) {
    int i = blockIdx.x * 256 + threadIdx.x;
    if (i >= MASK_N) return;
    uint32_t a0 = 0u, a1 = 0u; tf_block(0u, 42u, a0, a1);
    uint32_t b0 = 0u, b1 = 1u; tf_block(0u, 42u, b0, b1);
    uint32_t x0, x1;
    x0 = 0u; x1 = (uint32_t)i; tf_block(a0, a1, x0, x1);
    m1[i] = ((x0 ^ x1) >> 31) == 0u;
    x0 = 0u; x1 = (uint32_t)i; tf_block(b0, b1, x0, x1);
    m2[i] = ((x0 ^ x1) >> 31) == 0u;
}

__global__ __launch_bounds__(256) void prenet1_kernel(
    const float* __restrict__ dec_in, const float* __restrict__ w1,
    const unsigned char* __restrict__ m1, float* __restrict__ x)
{
    int r = blockIdx.x;
    int t = r >> 6, b = r & 63;
    int tid = threadIdx.x;
    __shared__ float ds[NMEL];
    if (tid < NMEL) ds[tid] = (t == 0) ? 0.f : dec_in[(size_t)b * 40000 + tid * 500 + (t - 1)];
    __syncthreads();
    float acc = 0.f;
    const float* w = w1 + tid * NMEL;
#pragma unroll
    for (int k = 0; k < NMEL; ++k) acc += ds[k] * w[k];
    acc = fmaxf(acc, 0.f);
    int flat = r * 256 + tid;
    x[flat] = m1[flat] ? acc * 2.f : 0.f;
}

__global__ __launch_bounds__(256) void prenet2_kernel(
    const float* __restrict__ w2, const unsigned char* __restrict__ m2, float* x)
{
    int r = blockIdx.x;
    int tid = threadIdx.x;
    __shared__ float xs[PREN];
    xs[tid] = x[r * 256 + tid];
    __syncthreads();
    float acc = 0.f;
    const float* w = w2 + tid * PREN;
#pragma unroll 8
    for (int k = 0; k < PREN; ++k) acc += xs[k] * w[k];
    acc = fmaxf(acc, 0.f);
    int flat = r * 256 + tid;
    x[flat] = m2[flat] ? acc * 2.f : 0.f;
}

__global__ __launch_bounds__(128) void pm_kernel(
    const float* __restrict__ memory, const float* __restrict__ wm, float* __restrict__ pm)
{
    int b = blockIdx.x, t = blockIdx.y;
    int tid = threadIdx.x;
    __shared__ float ms[ENC];
    for (int i = tid; i < ENC; i += 128) ms[i] = memory[(size_t)b * (TIN * ENC) + (size_t)t * ENC + i];
    __syncthreads();
    float acc = 0.f;
    const float* w = wm + tid * ENC;
#pragma unroll 8
    for (int k = 0; k < ENC; ++k) acc += ms[k] * w[k];
    pm[(size_t)b * (TIN * ATTD) + t * ATTD + tid] = acc;
}

// one-time weight split+pack (fragment-contiguous B lines)
__global__ __launch_bounds__(256) void wpack_kernel(
    const float* __restrict__ w1, int K1, const float* __restrict__ w2, int K2,
    u16* __restrict__ dst)
{
    const int K = K1 + K2;
    int idx = blockIdx.x * 256 + threadIdx.x;
    if (idx >= 4096 * K) return;
    int n = idx / K, k = idx % K;
    float v = (k < K1) ? w1[n * K1 + k] : w2[n * K2 + (k - K1)];
    u16 h, l;
    split1(v, h, l);
    int tile = n >> 4, kc = k >> 5;
    int lane = (n & 15) + (((k & 31) >> 3) << 4);
    size_t off = ((size_t)(tile * (K >> 5) + kc) * 2) * 512 + lane * 8 + (k & 7);
    dst[off] = h;
    dst[off + 512] = l;
}

// ---------------- fp32 fallback K-split GEMM ----------------
struct SmemGemm { float Xs[32][68]; float Ws[32][68]; };

__device__ void gemm_phase(
    const float* __restrict__ X1, int ldx1, int kx1,
    const float* __restrict__ X2, int ldx2,
    const float* __restrict__ W1, int ldw1, int kw1,
    const float* __restrict__ W2, int ldw2,
    float* __restrict__ outp, int Kq, int blk, SmemGemm& s)
{
    const int tid = threadIdx.x;
    const int n0 = (blk & 63) * 64;
    const int ks = blk >> 6;
    const int kbeg = ks * Kq;
    const int tn = tid & 15, tm = tid >> 4;
    float acc[4][4];
#pragma unroll
    for (int i = 0; i < 4; ++i)
#pragma unroll
        for (int j = 0; j < 4; ++j) acc[i][j] = 0.f;

#pragma unroll 1
    for (int k0 = kbeg; k0 < kbeg + Kq; k0 += 32) {
#pragma unroll
        for (int i = 0; i < 8; ++i) {
            int flat = i * 256 + tid;
            int m = flat >> 5, c = flat & 31;
            int k = k0 + c;
            s.Xs[c][m] = (k < kx1) ? X1[m * ldx1 + k] : X2[m * ldx2 + (k - kx1)];
        }
#pragma unroll
        for (int i = 0; i < 8; ++i) {
            int flat = i * 256 + tid;
            int r = flat >> 5, c = flat & 31;
            int k = k0 + c;
            int n = n0 + r;
            s.Ws[c][r] = (k < kw1) ? W1[n * ldw1 + k] : W2[n * ldw2 + (k - kw1)];
        }
        __syncthreads();
#pragma unroll
        for (int kk = 0; kk < 32; ++kk) {
            float4 xv = *(const float4*)&s.Xs[kk][tm * 4];
            float4 wv = *(const float4*)&s.Ws[kk][tn * 4];
            float xr[4] = { xv.x, xv.y, xv.z, xv.w };
            float wr[4] = { wv.x, wv.y, wv.z, wv.w };
#pragma unroll
            for (int i = 0; i < 4; ++i)
#pragma unroll
                for (int j = 0; j < 4; ++j) acc[i][j] += xr[i] * wr[j];
        }
        __syncthreads();
    }
    float* o = outp + (size_t)ks * 64 * 4096;
#pragma unroll
    for (int i = 0; i < 4; ++i)
#pragma unroll
        for (int j = 0; j < 4; ++j)
            o[(tm * 4 + i) * 4096 + (n0 + tn * 4 + j)] = acc[i][j];
}

__global__ __launch_bounds__(256, 2) void pair_gemm(
    const float* __restrict__ xcat_dec,
    const float* __restrict__ dec_wih, const float* __restrict__ dec_whh,
    float* __restrict__ g2,
    const float* __restrict__ x, const float* __restrict__ xcat_att,
    const float* __restrict__ att_wih, const float* __restrict__ att_whh,
    float* __restrict__ g1, int t)
{
    __shared__ __align__(16) SmemGemm sm;
    const int blk = blockIdx.x;
    if (blk < 256) {
        if (t < 0) return;
        gemm_phase(xcat_dec, 2560, 2560, xcat_dec, 2560,
                   dec_wih, 1536, 1536, dec_whh, 1024, g2, 640, blk, sm);
    } else {
        const int tn = t + 1;
        if (tn >= TOUT) return;
        gemm_phase(x + (size_t)tn * (NB * PREN), PREN, PREN, xcat_att, 1536,
                   att_wih, 768, 768, att_whh, 1024, g1, 448, blk - 256, sm);
    }
}

// ---------------- MFMA gemm inner body over a kc list ----------------
__device__ __forceinline__ void mfma_tile_run(
    const u16* __restrict__ Ah, const u16* __restrict__ Al, int aoff,
    const float* __restrict__ xr,
    const u16* __restrict__ bp, int kc_beg, int nchunk, int kc_wrap_at, int kc_wrap_to,
    f32x4& acc, int lane)
{
    const int kg = lane >> 4;
#pragma unroll 4
    for (int i = 0; i < nchunk; ++i) {
        int kc = kc_beg + i;
        if (kc >= kc_wrap_at) kc = kc_wrap_to + (kc - kc_wrap_at);
        const int k = kc * 32 + kg * 8;
        bf16x8 ah, al;
        if (xr && k < 256) {
            float4 f0 = *(const float4*)(xr + k);
            float4 f1 = *(const float4*)(xr + k + 4);
            split8(f0, f1, ah, al);
        } else {
            ah = *(const bf16x8*)(Ah + (k - aoff));
            al = *(const bf16x8*)(Al + (k - aoff));
        }
        const u16* c0 = bp + (size_t)kc * 1024;
        bf16x8 bh = *(const bf16x8*)c0;
        bf16x8 bl = *(const bf16x8*)(c0 + 512);
        acc = MFMA16(ah, bh, acc); acc = MFMA16(ah, bl, acc); acc = MFMA16(al, bh, acc);
    }
}

__device__ __forceinline__ void mfma_store(float* o, f32x4 acc, int tile, int wave, int lane)
{
    const int n0 = tile * 16;
    const int mbase = wave * 16 + (lane >> 4) * 4;
    const int lr = lane & 15;
#pragma unroll
    for (int r = 0; r < 4; ++r)
        o[(mbase + r) * 4096 + n0 + lr] = acc[r];
}

// ---------------- energies device body ----------------
__device__ void energies_body(
    int b, int tc,
    const float* __restrict__ aw, const float* __restrict__ awc,
    const float* __restrict__ lc, const float* __restrict__ ld,
    const float* __restrict__ vvec, const float* __restrict__ pq,
    const float* __restrict__ pm, float* __restrict__ energ)
{
    const int t0 = tc * 64;
    const int tid = threadIdx.x;
    __shared__ float awin[96], awcin[96];
    __shared__ float lcs[NFILT * 62];
    __shared__ float locs[64 * 33];
    __shared__ float pqs[ATTD], vs[ATTD];
    __shared__ float ldm[ATTD * 33];

    for (int i = tid; i < 94; i += 256) {
        int t = t0 + i - CPAD;
        bool ok = (t >= 0 && t < TIN);
        awin[i]  = ok ? aw[b * TIN + t]  : 0.f;
        awcin[i] = ok ? awc[b * TIN + t] : 0.f;
    }
    for (int i = tid; i < NFILT * 62; i += 256) lcs[i] = lc[i];
    for (int i = tid; i < ATTD * NFILT; i += 256) ldm[(i >> 5) * 33 + (i & 31)] = ld[i];
    if (tid < ATTD) { pqs[tid] = pq[b * ATTD + tid]; vs[tid] = vvec[tid]; }
    __syncthreads();

    for (int idx = tid; idx < 64 * 32; idx += 256) {
        int tl = idx >> 5, f = idx & 31;
        const float* w0 = lcs + f * 62;
        float s = 0.f;
#pragma unroll
        for (int k = 0; k < KSZ; ++k)
            s += awin[tl + k] * w0[k] + awcin[tl + k] * w0[31 + k];
        locs[tl * 33 + f] = s;
    }
    __syncthreads();

    const int tl = tid >> 2, q = tid & 3;
    const int a0 = q * 32;
    const float* pmrow = pm + (size_t)b * (TIN * ATTD) + (size_t)(t0 + tl) * ATTD + a0;
    const float* lt = locs + tl * 33;
    float4 pv[8];
#pragma unroll
    for (int u = 0; u < 8; ++u) pv[u] = *(const float4*)&pmrow[u * 4];
    float e = 0.f;
#pragma unroll
    for (int aa = 0; aa < 32; ++aa) {
        int a = a0 + aa;
        float sv = pqs[a] + ((const float*)pv)[aa];
        const float* lrow = ldm + a * 33;
#pragma unroll
        for (int f = 0; f < NFILT; ++f) sv += lt[f] * lrow[f];
        e += vs[a] * tanhf_fast(sv);
    }
    e += __shfl_xor(e, 1);
    e += __shfl_xor(e, 2);
    if (q == 0) energ[b * TIN + t0 + tl] = e;
}

// ---------------- MID: energies(t) [blk 0-511] || gemm2-early(t) [512-1023] ----------------
__global__ __launch_bounds__(256) void fused_mid(
    const float* __restrict__ aw, const float* __restrict__ awc,
    const float* __restrict__ lc, const float* __restrict__ ld,
    const float* __restrict__ vvec, const float* __restrict__ pq,
    const float* __restrict__ pm, float* __restrict__ energ,
    const u16* __restrict__ xdech, const u16* __restrict__ xdecl,
    const u16* __restrict__ pk2, float* __restrict__ g2, int t)
{
    const int blk = blockIdx.x;
    if (t < 0) return;
    if (blk < 512) {
        energies_body(blk >> 3, blk & 7, aw, awc, lc, ld, vvec, pq, pm, energ);
        return;
    }
    const int tid = threadIdx.x;
    const int wave = tid >> 6, lane = tid & 63;
    const int mrow = wave * 16 + (lane & 15);
    f32x4 acc = {0.f, 0.f, 0.f, 0.f};
    // gemm2 early: ah chunks [0,32) (ks=0) or dh chunks [48,80) (ks=1)
    const int r = blk - 512;
    const int tile = r & 255, ks = r >> 8;
    const u16* bp = pk2 + (size_t)tile * NCH2 * 1024 + lane * 8;
    mfma_tile_run(xdech + mrow * 2560, xdecl + mrow * 2560, 0, nullptr,
                  bp, ks == 0 ? 0 : 48, 32, 1000, 0, acc, lane);
    mfma_store(g2 + (size_t)ks * 262144, acc, tile, wave, lane);
}

// ---------------- SM: softmax+ctx(t) [blk 0-511] || gemm1-early(t+1) [512-1023] ----------------
__global__ __launch_bounds__(256) void fused_sm(
    const float* __restrict__ energ, const int* __restrict__ mlen,
    const float* __restrict__ memory,
    float* __restrict__ aw, float* __restrict__ awc,
    float* __restrict__ out_align, int t,
    float* __restrict__ xcat_att, float* __restrict__ xcat_dec,
    u16* __restrict__ tailh, u16* __restrict__ taill,
    u16* __restrict__ xdech, u16* __restrict__ xdecl,
    const float* __restrict__ x,
    const u16* __restrict__ pk1, float* __restrict__ g1)
{
    const int blk = blockIdx.x;
    const int tid = threadIdx.x;

    if (blk >= 512) {
        // gemm1 early for t+1: ks=0 -> ah chunks [24,44); ks=1 -> [44,56) then x [0,8)
        const int tn = t + 1;
        if (tn >= TOUT) return;
        const int wave = tid >> 6, lane = tid & 63;
        const int mrow = wave * 16 + (lane & 15);
        f32x4 acc = {0.f, 0.f, 0.f, 0.f};
        const int r = blk - 512;
        const int tile = r & 255, ks = r >> 8;
        const u16* bp = pk1 + (size_t)tile * NCH1 * 1024 + lane * 8;
        const float* xr = x + ((size_t)tn * 64 + mrow) * 256;
        mfma_tile_run(tailh + mrow * 1536, taill + mrow * 1536, 256, xr,
                      bp, ks == 0 ? 24 : 44, 20, 56, 0, acc, lane);
        mfma_store(g1 + (size_t)ks * 262144, acc, tile, wave, lane);
        return;
    }

    // softmax + ctx for (b, dq)
    if (t < 0) return;
    const int b = blk >> 3, dq = blk & 7;
    const int len = mlen[b];
    __shared__ float es[TIN];
    __shared__ float red[256];

    float e1 = (tid < len) ? energ[b * TIN + tid] : -INFINITY;
    float e2 = (tid + 256 < len) ? energ[b * TIN + tid + 256] : -INFINITY;
    red[tid] = fmaxf(e1, e2);
    __syncthreads();
    for (int s = 128; s > 0; s >>= 1) {
        if (tid < s) red[tid] = fmaxf(red[tid], red[tid + s]);
        __syncthreads();
    }
    const float mx = red[0];
    __syncthreads();
    float p1 = __expf(e1 - mx);
    float p2 = __expf(e2 - mx);
    red[tid] = p1 + p2;
    __syncthreads();
    for (int s = 128; s > 0; s >>= 1) {
        if (tid < s) red[tid] += red[tid + s];
        __syncthreads();
    }
    const float inv = 1.f / red[0];
    p1 *= inv; p2 *= inv;
    es[tid] = p1; es[tid + 256] = p2;
    __syncthreads();

    if (tid < 64) {
        int tt = dq * 64 + tid;
        float p = es[tt];
        aw[b * TIN + tt] = p;
        awc[b * TIN + tt] += p;
        out_align[(size_t)b * (TOUT * TIN) + (size_t)t * TIN + tt] = p;
    }

    const int d = dq * 64 + (tid & 63), th = tid >> 6;
    const float* mb = memory + (size_t)b * (TIN * ENC);
    float accv = 0.f;
#pragma unroll 4
    for (int tt = th * 128; tt < th * 128 + 128; ++tt)
        accv += es[tt] * mb[(size_t)tt * ENC + d];
    red[tid] = accv;
    __syncthreads();
    if (tid < 64) {
        float cv = (red[tid] + red[tid + 64]) + (red[tid + 128] + red[tid + 192]);
        int dd = dq * 64 + tid;
        xcat_att[b * 1536 + dd] = cv;
        xcat_dec[b * 2560 + 1024 + dd] = cv;
        u16 h, l; split1(cv, h, l);
        tailh[b * 1536 + dd] = h;        taill[b * 1536 + dd] = l;
        xdech[b * 2560 + 1024 + dd] = h; xdecl[b * 2560 + 1024 + dd] = l;
    }
}

// ---------------- LATE: ctx K-chunks -> partial 2 of g2(t) and g1(t+1) ----------------
__global__ __launch_bounds__(256) void gemm_late(
    const u16* __restrict__ xdech, const u16* __restrict__ xdecl,
    const u16* __restrict__ pk2, float* __restrict__ g2,
    const u16* __restrict__ tailh, const u16* __restrict__ taill,
    const u16* __restrict__ pk1, float* __restrict__ g1, int t)
{
    const int blk = blockIdx.x;
    const int tid = threadIdx.x;
    const int wave = tid >> 6, lane = tid & 63;
    const int mrow = wave * 16 + (lane & 15);
    f32x4 acc = {0.f, 0.f, 0.f, 0.f};

    if (blk < 256) {
        if (t < 0) return;
        const int tile = blk;
        const u16* bp = pk2 + (size_t)tile * NCH2 * 1024 + lane * 8;
        mfma_tile_run(xdech + mrow * 2560, xdecl + mrow * 2560, 0, nullptr,
                      bp, 32, 16, 1000, 0, acc, lane);
        mfma_store(g2 + (size_t)2 * 262144, acc, tile, wave, lane);
    } else {
        const int tn = t + 1;
        if (tn >= TOUT) return;
        const int tile = blk - 256;
        const u16* bp = pk1 + (size_t)tile * NCH1 * 1024 + lane * 8;
        mfma_tile_run(tailh + mrow * 1536, taill + mrow * 1536, 256, nullptr,
                      bp, 8, 16, 1000, 0, acc, lane);
        mfma_store(g1 + (size_t)2 * 262144, acc, tile, wave, lane);
    }
}

// ---------------- L1: att_pointwise(t) || dec_pointwise+proj(t-1) ----------------
__global__ __launch_bounds__(256) void pair_pw(
    const float* __restrict__ g1, const float* __restrict__ att_bih, const float* __restrict__ att_bhh,
    float* __restrict__ ac, float* __restrict__ xcat_att, float* __restrict__ xcat_dec,
    const float* __restrict__ wq, float* __restrict__ pq,
    const float* __restrict__ g2, const float* __restrict__ dec_bih, const float* __restrict__ dec_bhh,
    float* __restrict__ dc, const float* __restrict__ proj_w, const float* __restrict__ proj_b,
    const float* __restrict__ gate_w, const float* __restrict__ gate_b,
    float* __restrict__ out,
    u16* __restrict__ tailh, u16* __restrict__ taill,
    u16* __restrict__ xdech, u16* __restrict__ xdecl,
    int nsplit, int t)
{
    const int tid = threadIdx.x;
    __shared__ float sbuf[1536];
    __shared__ float red[256];

    if (blockIdx.x < 64) {
        if (t >= TOUT) return;
        const int b = blockIdx.x;
#pragma unroll
        for (int q = 0; q < 4; ++q) {
            int j = q * 256 + tid;
            float gi = att_bih[j] + att_bhh[j];
            float gf = att_bih[1024 + j] + att_bhh[1024 + j];
            float gg = att_bih[2048 + j] + att_bhh[2048 + j];
            float go = att_bih[3072 + j] + att_bhh[3072 + j];
            for (int s = 0; s < nsplit; ++s) {
                const float* g = g1 + (size_t)s * 262144 + b * 4096;
                gi += g[j]; gf += g[1024 + j]; gg += g[2048 + j]; go += g[3072 + j];
            }
            float c = sigf(gf) * ac[b * 1024 + j] + sigf(gi) * tanhf_fast(gg);
            float h = sigf(go) * tanhf_fast(c);
            ac[b * 1024 + j] = c;
            xcat_att[b * 1536 + 512 + j] = h;
            xcat_dec[b * 2560 + j] = h;
            u16 hh, hl; split1(h, hh, hl);
            tailh[b * 1536 + 512 + j] = hh;  taill[b * 1536 + 512 + j] = hl;
            xdech[b * 2560 + j] = hh;        xdecl[b * 2560 + j] = hl;
            sbuf[j] = h;
        }
        __syncthreads();
        const int a = tid & 127, half = tid >> 7;
        const float* wr = wq + a * 1024 + half * 512;
        const float* hh = sbuf + half * 512;
        float s0 = 0.f, s1 = 0.f, s2 = 0.f, s3 = 0.f;
#pragma unroll 4
        for (int k = 0; k < 512; k += 16) {
            float4 w0 = *(const float4*)&wr[k],      h0 = *(const float4*)&hh[k];
            float4 w1 = *(const float4*)&wr[k + 4],  h1 = *(const float4*)&hh[k + 4];
            float4 w2 = *(const float4*)&wr[k + 8],  h2 = *(const float4*)&hh[k + 8];
            float4 w3 = *(const float4*)&wr[k + 12], h3 = *(const float4*)&hh[k + 12];
            s0 += h0.x * w0.x + h0.y * w0.y + h0.z * w0.z + h0.w * w0.w;
            s1 += h1.x * w1.x + h1.y * w1.y + h1.z * w1.z + h1.w * w1.w;
            s2 += h2.x * w2.x + h2.y * w2.y + h2.z * w2.z + h2.w * w2.w;
            s3 += h3.x * w3.x + h3.y * w3.y + h3.z * w3.z + h3.w * w3.w;
        }
        red[tid] = (s0 + s1) + (s2 + s3);
        __syncthreads();
        if (half == 0) pq[b * 128 + a] = red[a] + red[a + 128];
    } else {
        if (t < 1) return;
        const int b = blockIdx.x - 64;
        const int ts = t - 1;
#pragma unroll
        for (int q = 0; q < 4; ++q) {
            int j = q * 256 + tid;
            float gi = dec_bih[j] + dec_bhh[j];
            float gf = dec_bih[1024 + j] + dec_bhh[1024 + j];
            float gg = dec_bih[2048 + j] + dec_bhh[2048 + j];
            float go = dec_bih[3072 + j] + dec_bhh[3072 + j];
            for (int s = 0; s < nsplit; ++s) {
                const float* g = g2 + (size_t)s * 262144 + b * 4096;
                gi += g[j]; gf += g[1024 + j]; gg += g[2048 + j]; go += g[3072 + j];
            }
            float c = sigf(gf) * dc[b * 1024 + j] + sigf(gi) * tanhf_fast(gg);
            float h = sigf(go) * tanhf_fast(c);
            dc[b * 1024 + j] = c;
            xcat_dec[b * 2560 + 1536 + j] = h;
            u16 hh, hl; split1(h, hh, hl);
            xdech[b * 2560 + 1536 + j] = hh;  xdecl[b * 2560 + 1536 + j] = hl;
            sbuf[j] = h;
        }
        for (int i = tid; i < 512; i += 256) sbuf[1024 + i] = xcat_dec[b * 2560 + 1024 + i];
        __syncthreads();
        const int o = tid >> 1, half = tid & 1;
        float accv = 0.f;
        if (o <= 80) {
            const float* w = (o < 80) ? (proj_w + o * 1536) : gate_w;
            const float* sv = sbuf + half * 768;
            const float* wv = w + half * 768;
            float s0 = 0.f, s1 = 0.f, s2 = 0.f, s3 = 0.f;
#pragma unroll 4
            for (int k = 0; k < 768; k += 16) {
                float4 a0 = *(const float4*)&sv[k],      b0 = *(const float4*)&wv[k];
                float4 a1 = *(const float4*)&sv[k + 4],  b1 = *(const float4*)&wv[k + 4];
                float4 a2 = *(const float4*)&sv[k + 8],  b2 = *(const float4*)&wv[k + 8];
                float4 a3 = *(const float4*)&sv[k + 12], b3 = *(const float4*)&wv[k + 12];
                s0 += a0.x * b0.x + a0.y * b0.y + a0.z * b0.z + a0.w * b0.w;
                s1 += a1.x * b1.x + a1.y * b1.y + a1.z * b1.z + a1.w * b1.w;
                s2 += a2.x * b2.x + a2.y * b2.y + a2.z * b2.z + a2.w * b2.w;
                s3 += a3.x * b3.x + a3.y * b3.y + a3.z * b3.z + a3.w * b3.w;
            }
            accv = (s0 + s1) + (s2 + s3);
        }
        red[tid] = accv;
        __syncthreads();
        if (half == 0 && o <= 80) {
            float r = red[tid] + red[tid + 1];
            if (o < 80)
                out[MEL_OFF + (size_t)b * (TOUT * NMEL) + (size_t)ts * NMEL + o] = r + proj_b[o];
            else
                out[GATE_OFF + (size_t)b * TOUT + ts] = r + gate_b[0];
        }
    }
}

// ---------------- fallback kernels (fp32 path) ----------------
__global__ __launch_bounds__(256) void energies_kernel(
    const float* __restrict__ aw, const float* __restrict__ awc,
    const float* __restrict__ lc, const float* __restrict__ ld,
    const float* __restrict__ vvec, const float* __restrict__ pq,
    const float* __restrict__ pm, float* __restrict__ energ)
{
    energies_body(blockIdx.x >> 3, blockIdx.x & 7, aw, awc, lc, ld, vvec, pq, pm, energ);
}

__global__ __launch_bounds__(256) void softmax_ctx_kernel(
    const float* __restrict__ energ, const int* __restrict__ mlen,
    const float* __restrict__ memory,
    float* __restrict__ aw, float* __restrict__ awc,
    float* __restrict__ out_align, int t_step,
    float* __restrict__ xcat_att, float* __restrict__ xcat_dec,
    u16* __restrict__ tailh, u16* __restrict__ taill,
    u16* __restrict__ xdech, u16* __restrict__ xdecl)
{
    const int b = blockIdx.x >> 3, dq = blockIdx.x & 7;
    const int tid = threadIdx.x;
    const int len = mlen[b];
    __shared__ float es[TIN];
    __shared__ float red[256];

    float e1 = (tid < len) ? energ[b * TIN + tid] : -INFINITY;
    float e2 = (tid + 256 < len) ? energ[b * TIN + tid + 256] : -INFINITY;
    red[tid] = fmaxf(e1, e2);
    __syncthreads();
    for (int s = 128; s > 0; s >>= 1) {
        if (tid < s) red[tid] = fmaxf(red[tid], red[tid + s]);
        __syncthreads();
    }
    const float mx = red[0];
    __syncthreads();
    float p1 = __expf(e1 - mx);
    float p2 = __expf(e2 - mx);
    red[tid] = p1 + p2;
    __syncthreads();
    for (int s = 128; s > 0; s >>= 1) {
        if (tid < s) red[tid] += red[tid + s];
        __syncthreads();
    }
    const float inv = 1.f / red[0];
    p1 *= inv; p2 *= inv;
    es[tid] = p1; es[tid + 256] = p2;
    __syncthreads();

    if (tid < 64) {
        int tt = dq * 64 + tid;
        float p = es[tt];
        aw[b * TIN + tt] = p;
        awc[b * TIN + tt] += p;
        out_align[(size_t)b * (TOUT * TIN) + (size_t)t_step * TIN + tt] = p;
    }

    const int d = dq * 64 + (tid & 63), th = tid >> 6;
    const float* mb = memory + (size_t)b * (TIN * ENC);
    float accv = 0.f;
#pragma unroll 4
    for (int tt = th * 128; tt < th * 128 + 128; ++tt)
        accv += es[tt] * mb[(size_t)tt * ENC + d];
    red[tid] = accv;
    __syncthreads();
    if (tid < 64) {
        float cv = (red[tid] + red[tid + 64]) + (red[tid + 128] + red[tid + 192]);
        int dd = dq * 64 + tid;
        xcat_att[b * 1536 + dd] = cv;
        xcat_dec[b * 2560 + 1024 + dd] = cv;
        u16 h, l; split1(cv, h, l);
        tailh[b * 1536 + dd] = h;        taill[b * 1536 + dd] = l;
        xdech[b * 2560 + 1024 + dd] = h; xdecl[b * 2560 + 1024 + dd] = l;
    }
}

extern "C" void kernel_launch(void* const* d_in, const int* in_sizes, int n_in,
                              void* d_out, int out_size, void* d_ws, size_t ws_size,
                              hipStream_t stream) {
    const float* memory   = (const float*)d_in[0];
    const float* dec_in   = (const float*)d_in[1];
    const int*   mlen     = (const int*)d_in[2];
    const float* pw1      = (const float*)d_in[3];
    const float* pw2      = (const float*)d_in[4];
    const float* att_wih  = (const float*)d_in[5];
    const float* att_whh  = (const float*)d_in[6];
    const float* att_bih  = (const float*)d_in[7];
    const float* att_bhh  = (const float*)d_in[8];
    const float* wq       = (const float*)d_in[9];
    const float* wm       = (const float*)d_in[10];
    const float* v        = (const float*)d_in[11];
    const float* loc_conv = (const float*)d_in[12];
    const float* loc_dense= (const float*)d_in[13];
    const float* dec_wih  = (const float*)d_in[14];
    const float* dec_whh  = (const float*)d_in[15];
    const float* dec_bih  = (const float*)d_in[16];
    const float* dec_bhh  = (const float*)d_in[17];
    const float* proj_w   = (const float*)d_in[18];
    const float* proj_b   = (const float*)d_in[19];
    const float* gate_w   = (const float*)d_in[20];
    const float* gate_b   = (const float*)d_in[21];
    float* out = (float*)d_out;

    // ---- ws layout ----
    float* x        = (float*)d_ws;
    float* pm       = x + X_SZ;
    float* g1       = pm + PM_SZ;
    float* g2       = g1 + G1_SZ;
    float* xcat_att = g2 + G2_SZ;          // zero-block start
    float* xcat_dec = xcat_att + XATT_SZ;
    float* ac       = xcat_dec + XDEC_SZ;
    float* dc       = ac + AC_SZ;
    float* aw       = dc + DC_SZ;
    float* awc      = aw + AW_SZ;
    float* tailh_f  = awc + AWC_SZ;
    float* taill_f  = tailh_f + TAILH_SZ;
    float* xdech_f  = taill_f + TAILL_SZ;
    float* xdecl_f  = xdech_f + XDH_SZ;    // zero-block end
    float* pq       = xdecl_f + XDL_SZ;
    float* energ    = pq + PQ_SZ;
    unsigned char* m1 = (unsigned char*)(energ + EN_SZ);
    unsigned char* m2 = m1 + MASK_N;
    u16* pk1 = (u16*)(m2 + MASK_N);
    u16* pk2 = pk1 + PK1_N;

    u16* tailh = (u16*)tailh_f;  u16* taill = (u16*)taill_f;
    u16* xdech = (u16*)xdech_f;  u16* xdecl = (u16*)xdecl_f;

    size_t need_base = (size_t)(m2 + MASK_N - (unsigned char*)d_ws);
    size_t need_full = (size_t)((unsigned char*)(pk2 + PK2_N) - (unsigned char*)d_ws);
    if (ws_size < need_base) return;
    const bool use_mfma = (ws_size >= need_full);
    const int nsplit = use_mfma ? 3 : 4;

    // zero recurrent state (xcat_att .. xdecl contiguous)
    size_t state_floats = (size_t)XATT_SZ + XDEC_SZ + AC_SZ + DC_SZ + AW_SZ + AWC_SZ
                        + TAILH_SZ + TAILL_SZ + XDH_SZ + XDL_SZ;
    hipMemsetAsync(xcat_att, 0, state_floats * sizeof(float), stream);

    // one-time: dropout masks, prenet, processed memory, weight pack
    mask_kernel<<<(MASK_N + 255) / 256, 256, 0, stream>>>(m1, m2);
    prenet1_kernel<<<TOUT * NB, 256, 0, stream>>>(dec_in, pw1, m1, x);
    prenet2_kernel<<<TOUT * NB, 256, 0, stream>>>(pw2, m2, x);
    pm_kernel<<<dim3(NB, TIN), 128, 0, stream>>>(memory, wm, pm);
    if (use_mfma) {
        wpack_kernel<<<(4096 * K1TOT + 255) / 256, 256, 0, stream>>>(att_wih, 768, att_whh, 1024, pk1);
        wpack_kernel<<<(4096 * K2TOT + 255) / 256, 256, 0, stream>>>(dec_wih, 1536, dec_whh, 1024, pk2);
    }

    float* out_align = out + ALGN_OFF;

    // prologue: gemm1(0) early (fused_sm with t=-1 runs only gemm1 blocks) + late
    if (use_mfma) {
        fused_sm<<<1024, 256, 0, stream>>>(energ, mlen, memory, aw, awc, out_align, -1,
                                           xcat_att, xcat_dec, tailh, taill, xdech, xdecl,
                                           x, pk1, g1);
        gemm_late<<<512, 256, 0, stream>>>(xdech, xdecl, pk2, g2, tailh, taill, pk1, g1, -1);
    } else {
        pair_gemm<<<512, 256, 0, stream>>>(xcat_dec, dec_wih, dec_whh, g2,
                                           x, xcat_att, att_wih, att_whh, g1, -1);
    }

    for (int t = 0; t < TOUT; ++t) {
        pair_pw<<<128, 256, 0, stream>>>(g1, att_bih, att_bhh, ac, xcat_att, xcat_dec, wq, pq,
                                         g2, dec_bih, dec_bhh, dc, proj_w, proj_b,
                                         gate_w, gate_b, out, tailh, taill, xdech, xdecl,
                                         nsplit, t);
        if (use_mfma) {
            // energies(t) || gemm2-early(t)
            fused_mid<<<1024, 256, 0, stream>>>(aw, awc, loc_conv, loc_dense, v, pq, pm, energ,
                                                xdech, xdecl, pk2, g2, t);
            // softmax+ctx(t) || gemm1-early(t+1)
            fused_sm<<<1024, 256, 0, stream>>>(energ, mlen, memory, aw, awc, out_align, t,
                                               xcat_att, xcat_dec, tailh, taill, xdech, xdecl,
                                               x, pk1, g1);
            // ctx K-chunks of both gemms
            gemm_late<<<512, 256, 0, stream>>>(xdech, xdecl, pk2, g2, tailh, taill, pk1, g1, t);
        } else {
            energies_kernel<<<512, 256, 0, stream>>>(aw, awc, loc_conv, loc_dense, v, pq, pm, energ);
            softmax_ctx_kernel<<<512, 256, 0, stream>>>(energ, mlen, memory, aw, awc, out_align, t,
                                                        xcat_att, xcat_dec, tailh, taill, xdech, xdecl);
            pair_gemm<<<512, 256, 0, stream>>>(xcat_dec, dec_wih, dec_whh, g2,
                                               x, xcat_att, att_wih, att_whh, g1, t);
        }
    }
    // epilogue: dec_pointwise+proj for t=499
    pair_pw<<<128, 256, 0, stream>>>(g1, att_bih, att_bhh, ac, xcat_att, xcat_dec, wq, pq,
                                     g2, dec_bih, dec_bhh, dc, proj_w, proj_b,
                                     gate_w, gate_b, out, tailh, taill, xdech, xdecl,
                                     nsplit, TOUT);
}